// Round 4
// baseline (93.704 us; speedup 1.0000x reference)
//
#include <hip/hip_runtime.h>

// DarcyLoss: B=4096, C=2, H=W=64. Inputs (f32): model_out, target, x0_hat [B,2,64,64], var [B].
// Output: scalar f32 loss = mean((mo-tg)^2) + mean_b( min(0.5*r_b^2/var_b, 27.6310211159) )
// r_b = (sum(eq0) + sum(bc)) / (64*64*3);  source f_s sums to 0 -> omitted.
//
// Structure: TWO waves per batch (8192 waves -> 32 waves/CU = occupancy cap).
// Wave half=0: rows 0..31 + mo/tg float4-chunks 0..15.
// Wave half=1: rows 32..63 + chunks 16..31.  (2048 float4 per batch total;
// each chunk = 64 lanes x 1 float4.)  Lane j owns column j; vertical stencils
// via rolling register window; horizontal via __shfl. No LDS, no barriers.
// Partial sums combined in the final kernel (residual halves summed BEFORE
// square/clamp -> exact math).

#define NB 4096
#define HW 4096          // 64*64
#define CHW 8192         // 2*64*64

__device__ __forceinline__ void hderiv2(float v, int j, float& d1, float& d11) {
    constexpr float INV2D = 31.5f, INVD2 = 3969.0f;
    float vm = __shfl(v, (j + 63) & 63);   // j-1 (unused at j=0)
    float vp = __shfl(v, (j + 1) & 63);    // j+1 (unused at j=63)
    float v2 = __shfl(v, (j == 0) ? 2 : 61);
    float v3 = __shfl(v, (j == 0) ? 3 : 60);
    d1  = (vp - vm) * INV2D;
    d11 = (vp - 2.0f * v + vm) * INVD2;
    if (j == 0)  { d1 = (-3.0f * v + 4.0f * vp - v2) * INV2D;
                   d11 = (2.0f * v - 5.0f * vp + 4.0f * v2 - v3) * INVD2; }
    if (j == 63) { d1 = ( 3.0f * v - 4.0f * vm + v2) * INV2D;
                   d11 = (2.0f * v - 5.0f * vm + 4.0f * v2 - v3) * INVD2; }
}

__device__ __forceinline__ float hderiv1(float v, int j) {
    constexpr float INV2D = 31.5f;
    float vm = __shfl(v, (j + 63) & 63);
    float vp = __shfl(v, (j + 1) & 63);
    float v2 = __shfl(v, (j == 0) ? 2 : 61);
    float d = (vp - vm) * INV2D;
    if (j == 0)  d = (-3.0f * v + 4.0f * vp - v2) * INV2D;
    if (j == 63) d = ( 3.0f * v - 4.0f * vm + v2) * INV2D;
    return d;
}

__global__ __launch_bounds__(256, 8) void darcy_wave_kernel(
    const float* __restrict__ mo, const float* __restrict__ tg,
    const float* __restrict__ x0, float* __restrict__ ws_r, float* __restrict__ ws_d)
{
    constexpr float INV2D = 31.5f;
    constexpr float INVD2 = 3969.0f;

    const int wave = threadIdx.x >> 6;
    const int j    = threadIdx.x & 63;
    const int half = wave & 1;
    const int b    = blockIdx.x * 2 + (wave >> 1);

    const float*  pb = x0 + (size_t)b * CHW;        // p    plane
    const float*  qb = pb + HW;                     // perm plane
    const float4* m4 = (const float4*)(mo + (size_t)b * CHW);   // 2048 float4
    const float4* g4 = (const float4*)(tg + (size_t)b * CHW);

    float rsum = 0.0f, dsum = 0.0f;

    if (half == 0) {
        // ---- rows 0..31; chunks 0..15 ----
        float pm = pb[j], pc = pb[64 + j], pp = pb[128 + j], pn = pb[192 + j];
        float qm = qb[j], qc = qb[64 + j], qp = qb[128 + j], qn = qb[192 + j];

        // row 0 (one-sided vertical) + chunk 0
        {
            float4 a = m4[j], c = g4[j];
            float e0 = a.x - c.x, e1 = a.y - c.y, e2 = a.z - c.z, e3 = a.w - c.w;
            dsum += e0 * e0 + e1 * e1 + e2 * e2 + e3 * e3;

            float pd1, pd11;
            hderiv2(pm, j, pd1, pd11);
            float qd1 = hderiv1(qm, j);
            float pd0  = (-3.0f * pm + 4.0f * pc - pp) * INV2D;
            float pd00 = (2.0f * pm - 5.0f * pc + 4.0f * pp - pn) * INVD2;
            float qd0  = (-3.0f * qm + 4.0f * qc - qp) * INV2D;
            rsum += -qm * (pd00 + pd11) - qd0 * pd0 - qd1 * pd1 - pd0;   // bc(i=0)
            rsum += (j == 0) ? pd1 : 0.0f;
            rsum -= (j == 63) ? pd1 : 0.0f;
        }

        #pragma unroll 2
        for (int i = 1; i <= 31; ++i) {
            float pn2 = pb[((i + 3) << 6) + j];       // rows 4..34, in bounds
            float qn2 = qb[((i + 3) << 6) + j];
            if (i & 1) {                               // odd i: chunk (i+1)/2 = 1..15
                const int c4 = (((i + 1) >> 1) << 6) + j;
                float4 a = m4[c4], c = g4[c4];
                float e0 = a.x - c.x, e1 = a.y - c.y, e2 = a.z - c.z, e3 = a.w - c.w;
                dsum += e0 * e0 + e1 * e1 + e2 * e2 + e3 * e3;
            }

            float pd1, pd11;
            hderiv2(pc, j, pd1, pd11);
            float qd1 = hderiv1(qc, j);
            float pd0  = (pp - pm) * INV2D;
            float pd00 = (pp - 2.0f * pc + pm) * INVD2;
            float qd0  = (qp - qm) * INV2D;
            rsum += -qc * (pd00 + pd11) - qd0 * pd0 - qd1 * pd1;
            rsum += (j == 0) ? pd1 : 0.0f;
            rsum -= (j == 63) ? pd1 : 0.0f;

            pm = pc; pc = pp; pp = pn; pn = pn2;
            qm = qc; qc = qp; qp = qn; qn = qn2;
        }
    } else {
        // ---- rows 32..63; chunks 16..31 ----
        float pm = pb[31 * 64 + j], pc = pb[32 * 64 + j], pp = pb[33 * 64 + j], pn = pb[34 * 64 + j];
        float qm = qb[31 * 64 + j], qc = qb[32 * 64 + j], qp = qb[33 * 64 + j], qn = qb[34 * 64 + j];

        float s_p60 = 0.0f, s_p61 = 0.0f, s_q61 = 0.0f;

        #pragma unroll 2
        for (int i = 32; i <= 62; ++i) {
            float pn2 = 0.0f, qn2 = 0.0f;
            if (i <= 60) {
                pn2 = pb[((i + 3) << 6) + j];          // rows 35..63, in bounds
                qn2 = qb[((i + 3) << 6) + j];
            }
            if (!(i & 1)) {                            // even i: chunk 16+(i-32)/2 = 16..30
                const int c4 = ((16 + ((i - 32) >> 1)) << 6) + j;
                float4 a = m4[c4], c = g4[c4];
                float e0 = a.x - c.x, e1 = a.y - c.y, e2 = a.z - c.z, e3 = a.w - c.w;
                dsum += e0 * e0 + e1 * e1 + e2 * e2 + e3 * e3;
            }

            float pd1, pd11;
            hderiv2(pc, j, pd1, pd11);
            float qd1 = hderiv1(qc, j);
            float pd0  = (pp - pm) * INV2D;
            float pd00 = (pp - 2.0f * pc + pm) * INVD2;
            float qd0  = (qp - qm) * INV2D;
            rsum += -qc * (pd00 + pd11) - qd0 * pd0 - qd1 * pd1;
            rsum += (j == 0) ? pd1 : 0.0f;
            rsum -= (j == 63) ? pd1 : 0.0f;

            if (i == 61) s_p60 = pm;                 // pm = p[60]
            if (i == 62) { s_p61 = pm; s_q61 = qm; } // pm = p[61], qm = q[61]

            pm = pc; pc = pp; pp = pn; pn = pn2;
            qm = qc; qc = qp; qp = qn; qn = qn2;
        }

        // row 63 (one-sided vertical) + chunk 31;  window: pm=p62, pc=p63
        {
            const int c4 = (31 << 6) + j;              // max index 2047, in bounds
            float4 a = m4[c4], c = g4[c4];
            float e0 = a.x - c.x, e1 = a.y - c.y, e2 = a.z - c.z, e3 = a.w - c.w;
            dsum += e0 * e0 + e1 * e1 + e2 * e2 + e3 * e3;

            float pd1, pd11;
            hderiv2(pc, j, pd1, pd11);
            float qd1 = hderiv1(qc, j);
            float pd0  = (3.0f * pc - 4.0f * pm + s_p61) * INV2D;
            float pd00 = (2.0f * pc - 5.0f * pm + 4.0f * s_p61 - s_p60) * INVD2;
            float qd0  = (3.0f * qc - 4.0f * qm + s_q61) * INV2D;
            rsum += -qc * (pd00 + pd11) - qd0 * pd0 - qd1 * pd1 + pd0;   // bc(i=63)
            rsum += (j == 0) ? pd1 : 0.0f;
            rsum -= (j == 63) ? pd1 : 0.0f;
        }
    }

    // ---- per-wave reduction; write partials ----
    #pragma unroll
    for (int off = 32; off > 0; off >>= 1) {
        rsum += __shfl_down(rsum, off);
        dsum += __shfl_down(dsum, off);
    }
    if (j == 0) {
        ws_r[half * NB + b] = rsum;
        ws_d[half * NB + b] = dsum;
    }
}

__global__ __launch_bounds__(256) void darcy_final_kernel(
    const float* __restrict__ ws_r, const float* __restrict__ ws_d,
    const float* __restrict__ var, float* __restrict__ out)
{
    constexpr float CLAMP = 27.6310211159f;
    const int t = threadIdx.x;
    double rs = 0.0, ds = 0.0;
    for (int i = t; i < NB; i += 256) {
        const float rb = ws_r[i] + ws_r[NB + i];
        const float r  = rb * (1.0f / (64.0f * 64.0f * 3.0f));
        float res = 0.5f * r * r / var[i];
        rs += (double)fminf(res, CLAMP);
        ds += (double)(ws_d[i] + ws_d[NB + i]);
    }
    #pragma unroll
    for (int off = 32; off > 0; off >>= 1) {
        rs += __shfl_down(rs, off);
        ds += __shfl_down(ds, off);
    }
    __shared__ double red[8];
    const int wid = t >> 6, lane = t & 63;
    if (lane == 0) { red[wid] = rs; red[4 + wid] = ds; }
    __syncthreads();
    if (t == 0) {
        const double R  = red[0] + red[1] + red[2] + red[3];
        const double Dd = red[4] + red[5] + red[6] + red[7];
        out[0] = (float)(Dd / ((double)NB * (double)CHW) + R / (double)NB);
    }
}

extern "C" void kernel_launch(void* const* d_in, const int* in_sizes, int n_in,
                              void* d_out, int out_size, void* d_ws, size_t ws_size,
                              hipStream_t stream) {
    const float* mo  = (const float*)d_in[0];
    const float* tg  = (const float*)d_in[1];
    const float* x0  = (const float*)d_in[2];
    const float* var = (const float*)d_in[3];
    float* out = (float*)d_out;

    float* ws_r = (float*)d_ws;            // 2*NB floats
    float* ws_d = ws_r + 2 * NB;           // 2*NB floats

    darcy_wave_kernel<<<NB / 2, 256, 0, stream>>>(mo, tg, x0, ws_r, ws_d);
    darcy_final_kernel<<<1, 256, 0, stream>>>(ws_r, ws_d, var, out);
}

// Round 6
// 83.844 us; speedup vs baseline: 1.1176x; 1.1176x over previous
//
#include <hip/hip_runtime.h>

// DarcyLoss: B=4096, C=2, H=W=64. Inputs (f32): model_out, target, x0_hat [B,2,64,64], var [B].
// loss = mean((mo-tg)^2) + mean_b( min(0.5*r_b^2/var_b, 27.6310211159) )
// r_b = (sum(eq0)+sum(bc)) / (64*64*3);  source f_s sums to 0 -> omitted.
//
// R6 = R5 with the nontemporal loads using a clang ext_vector float4 (the HIP
// float4 struct is rejected by __builtin_nontemporal_load).
//  even blocks (1024): streaming reduction of (mo-tg)^2, nontemporal float4,
//    8 loads in flight per lane (mo/tg: zero reuse -> keep out of L2/L3).
//  odd blocks (1024): R2's stencil waves, 1 wave per batch, rolling register
//    window + __shfl horizontals; x0 cached (fits L3).
// No atomics -> deterministic. Final kernel reduces partials in double.

#define NB 4096
#define HW 4096          // 64*64
#define CHW 8192         // 2*64*64
#define N4 8388608       // float4 per array = NB*CHW/4
#define SBLOCKS 1024
#define STRIDE (SBLOCKS * 256)   // 262144 threads in streaming role
#define PER_TH (N4 / STRIDE)     // 32 float4 per thread per array

typedef float vf4 __attribute__((ext_vector_type(4)));

__device__ __forceinline__ void hderiv2(float v, int j, float& d1, float& d11) {
    constexpr float INV2D = 31.5f, INVD2 = 3969.0f;
    float vm = __shfl(v, (j + 63) & 63);
    float vp = __shfl(v, (j + 1) & 63);
    float v2 = __shfl(v, (j == 0) ? 2 : 61);
    float v3 = __shfl(v, (j == 0) ? 3 : 60);
    d1  = (vp - vm) * INV2D;
    d11 = (vp - 2.0f * v + vm) * INVD2;
    if (j == 0)  { d1 = (-3.0f * v + 4.0f * vp - v2) * INV2D;
                   d11 = (2.0f * v - 5.0f * vp + 4.0f * v2 - v3) * INVD2; }
    if (j == 63) { d1 = ( 3.0f * v - 4.0f * vm + v2) * INV2D;
                   d11 = (2.0f * v - 5.0f * vm + 4.0f * v2 - v3) * INVD2; }
}

__device__ __forceinline__ float hderiv1(float v, int j) {
    constexpr float INV2D = 31.5f;
    float vm = __shfl(v, (j + 63) & 63);
    float vp = __shfl(v, (j + 1) & 63);
    float v2 = __shfl(v, (j == 0) ? 2 : 61);
    float d = (vp - vm) * INV2D;
    if (j == 0)  d = (-3.0f * v + 4.0f * vp - v2) * INV2D;
    if (j == 63) d = ( 3.0f * v - 4.0f * vm + v2) * INV2D;
    return d;
}

__global__ __launch_bounds__(256, 8) void darcy_main_kernel(
    const float* __restrict__ mo, const float* __restrict__ tg,
    const float* __restrict__ x0, const float* __restrict__ var,
    float* __restrict__ ws_res, float* __restrict__ ws_d)
{
    constexpr float INV2D = 31.5f;
    constexpr float INVD2 = 3969.0f;
    constexpr float CLAMP = 27.6310211159f;

    if ((blockIdx.x & 1) == 0) {
        // ================= streaming role: (mo-tg)^2 partial sum =================
        const int sb  = blockIdx.x >> 1;               // 0..1023
        const int tid = sb * 256 + threadIdx.x;        // 0..262143
        const vf4* m4 = (const vf4*)mo;
        const vf4* g4 = (const vf4*)tg;

        float acc0 = 0.0f, acc1 = 0.0f, acc2 = 0.0f, acc3 = 0.0f;
        #pragma unroll
        for (int k = 0; k < PER_TH; k += 4) {
            const int i0 = tid + (k + 0) * STRIDE;
            const int i1 = tid + (k + 1) * STRIDE;
            const int i2 = tid + (k + 2) * STRIDE;
            const int i3 = tid + (k + 3) * STRIDE;
            vf4 a0 = __builtin_nontemporal_load(m4 + i0);
            vf4 a1 = __builtin_nontemporal_load(m4 + i1);
            vf4 a2 = __builtin_nontemporal_load(m4 + i2);
            vf4 a3 = __builtin_nontemporal_load(m4 + i3);
            vf4 c0 = __builtin_nontemporal_load(g4 + i0);
            vf4 c1 = __builtin_nontemporal_load(g4 + i1);
            vf4 c2 = __builtin_nontemporal_load(g4 + i2);
            vf4 c3 = __builtin_nontemporal_load(g4 + i3);
            vf4 d0 = a0 - c0, d1 = a1 - c1, d2 = a2 - c2, d3 = a3 - c3;
            acc0 += d0.x * d0.x + d1.x * d1.x + d2.x * d2.x + d3.x * d3.x;
            acc1 += d0.y * d0.y + d1.y * d1.y + d2.y * d2.y + d3.y * d3.y;
            acc2 += d0.z * d0.z + d1.z * d1.z + d2.z * d2.z + d3.z * d3.z;
            acc3 += d0.w * d0.w + d1.w * d1.w + d2.w * d2.w + d3.w * d3.w;
        }
        float dsum = (acc0 + acc1) + (acc2 + acc3);

        #pragma unroll
        for (int off = 32; off > 0; off >>= 1)
            dsum += __shfl_down(dsum, off);

        __shared__ float red[4];
        const int wid = threadIdx.x >> 6, lane = threadIdx.x & 63;
        if (lane == 0) red[wid] = dsum;
        __syncthreads();
        if (threadIdx.x == 0)
            ws_d[sb] = red[0] + red[1] + red[2] + red[3];
        return;
    }

    // ================= stencil role: residual per batch (R2 structure) =================
    const int wave = threadIdx.x >> 6;
    const int j    = threadIdx.x & 63;
    const int b    = (blockIdx.x >> 1) * 4 + wave;     // 0..4095

    const float* pb = x0 + (size_t)b * CHW;        // p    plane
    const float* qb = pb + HW;                     // perm plane

    float rsum = 0.0f;

    // preload rows 0..3
    float pm = pb[j], pc = pb[64 + j], pp = pb[128 + j], pn = pb[192 + j];
    float qm = qb[j], qc = qb[64 + j], qp = qb[128 + j], qn = qb[192 + j];

    // row i = 0 (one-sided vertical)
    {
        float pd1, pd11;
        hderiv2(pm, j, pd1, pd11);
        float qd1 = hderiv1(qm, j);
        float pd0  = (-3.0f * pm + 4.0f * pc - pp) * INV2D;
        float pd00 = (2.0f * pm - 5.0f * pc + 4.0f * pp - pn) * INVD2;
        float qd0  = (-3.0f * qm + 4.0f * qc - qp) * INV2D;
        rsum += -qm * (pd00 + pd11) - qd0 * pd0 - qd1 * pd1 - pd0;   // bc(i=0)
        rsum += (j == 0) ? pd1 : 0.0f;
        rsum -= (j == 63) ? pd1 : 0.0f;
    }

    float s_p60 = 0.0f, s_p61 = 0.0f, s_q61 = 0.0f;

    #pragma unroll 2
    for (int i = 1; i <= 62; ++i) {
        float pn2 = 0.0f, qn2 = 0.0f;
        if (i <= 60) {
            pn2 = pb[((i + 3) << 6) + j];
            qn2 = qb[((i + 3) << 6) + j];
        }

        float pd1, pd11;
        hderiv2(pc, j, pd1, pd11);
        float qd1 = hderiv1(qc, j);
        float pd0  = (pp - pm) * INV2D;
        float pd00 = (pp - 2.0f * pc + pm) * INVD2;
        float qd0  = (qp - qm) * INV2D;
        rsum += -qc * (pd00 + pd11) - qd0 * pd0 - qd1 * pd1;
        rsum += (j == 0) ? pd1 : 0.0f;
        rsum -= (j == 63) ? pd1 : 0.0f;

        if (i == 61) s_p60 = pm;                 // pm = p[60]
        if (i == 62) { s_p61 = pm; s_q61 = qm; } // pm = p[61], qm = q[61]

        pm = pc; pc = pp; pp = pn; pn = pn2;
        qm = qc; qc = qp; qp = qn; qn = qn2;
    }

    // row i = 63 (one-sided vertical); window: pm=p62, pc=p63
    {
        float pd1, pd11;
        hderiv2(pc, j, pd1, pd11);
        float qd1 = hderiv1(qc, j);
        float pd0  = (3.0f * pc - 4.0f * pm + s_p61) * INV2D;
        float pd00 = (2.0f * pc - 5.0f * pm + 4.0f * s_p61 - s_p60) * INVD2;
        float qd0  = (3.0f * qc - 4.0f * qm + s_q61) * INV2D;
        rsum += -qc * (pd00 + pd11) - qd0 * pd0 - qd1 * pd1 + pd0;   // bc(i=63)
        rsum += (j == 0) ? pd1 : 0.0f;
        rsum -= (j == 63) ? pd1 : 0.0f;
    }

    // per-wave reduction (wave == batch)
    #pragma unroll
    for (int off = 32; off > 0; off >>= 1)
        rsum += __shfl_down(rsum, off);

    if (j == 0) {
        const float r = rsum * (1.0f / (64.0f * 64.0f * 3.0f));
        float res = 0.5f * r * r / var[b];
        ws_res[b] = fminf(res, CLAMP);
    }
}

__global__ __launch_bounds__(256) void darcy_final_kernel(
    const float* __restrict__ ws_res, const float* __restrict__ ws_d,
    float* __restrict__ out)
{
    const int t = threadIdx.x;
    double rs = 0.0, ds = 0.0;
    for (int i = t; i < NB; i += 256) rs += (double)ws_res[i];
    for (int i = t; i < SBLOCKS; i += 256) ds += (double)ws_d[i];
    #pragma unroll
    for (int off = 32; off > 0; off >>= 1) {
        rs += __shfl_down(rs, off);
        ds += __shfl_down(ds, off);
    }
    __shared__ double red[8];
    const int wid = t >> 6, lane = t & 63;
    if (lane == 0) { red[wid] = rs; red[4 + wid] = ds; }
    __syncthreads();
    if (t == 0) {
        const double R  = red[0] + red[1] + red[2] + red[3];
        const double Dd = red[4] + red[5] + red[6] + red[7];
        out[0] = (float)(Dd / ((double)NB * (double)CHW) + R / (double)NB);
    }
}

extern "C" void kernel_launch(void* const* d_in, const int* in_sizes, int n_in,
                              void* d_out, int out_size, void* d_ws, size_t ws_size,
                              hipStream_t stream) {
    const float* mo  = (const float*)d_in[0];
    const float* tg  = (const float*)d_in[1];
    const float* x0  = (const float*)d_in[2];
    const float* var = (const float*)d_in[3];
    float* out = (float*)d_out;

    float* ws_res = (float*)d_ws;           // NB floats (clamped per-batch residual term)
    float* ws_d   = ws_res + NB;            // SBLOCKS floats (data-loss partials)

    darcy_main_kernel<<<2 * SBLOCKS, 256, 0, stream>>>(mo, tg, x0, var, ws_res, ws_d);
    darcy_final_kernel<<<1, 256, 0, stream>>>(ws_res, ws_d, out);
}